// Round 6
// baseline (482.129 us; speedup 1.0000x reference)
//
#include <hip/hip_runtime.h>
#include <stdint.h>
#include <math.h>

#define T_TOK 4096
#define H_DIM 1024
#define I_DIM 2048
#define E_NUM 8
#define PMAX (T_TOK * 2 + E_NUM * 128)  // 9216 padded dispatch rows upper bound

#define WCONV_BLOCKS (E_NUM * 512 * 3)  // 12288
#define ROUTER_BLOCKS (T_TOK / 4)       // 1024

typedef __attribute__((ext_vector_type(8))) short short8;
typedef __attribute__((ext_vector_type(4))) float f32x4;
typedef unsigned short u16;
typedef unsigned int u32;

__device__ __forceinline__ u16 f2bf(float f) {
  union { float f; u32 u; } v; v.f = f;
  u32 r = v.u + 0x7fffu + ((v.u >> 16) & 1u);  // round-to-nearest-even
  return (u16)(r >> 16);
}
__device__ __forceinline__ float bf2f(u16 a) {
  union { u32 u; float f; } v; v.u = ((u32)a) << 16; return v.f;
}

// async global->LDS DMA, 16 B per lane (m97 pattern; dest = wave base + lane*16)
__device__ __forceinline__ void async_ld16(const u16* g, u16* l) {
  __builtin_amdgcn_global_load_lds(
      (const __attribute__((address_space(1))) void*)g,
      (__attribute__((address_space(3))) void*)l, 16, 0, 0);
}

// ---------------- front: wconv (12288 blocks) + router/xcvt (1024 blocks) ----------------
// wconv branch: weight transpose+convert via register 4x4 micro-transpose (no LDS).
// router branch: stage gw -> LDS transposed, compute logits/softmax/top-2, emit xb.
__global__ void front_kernel(const float* __restrict__ Wg, const float* __restrict__ Wu,
                             const float* __restrict__ Wd, u16* __restrict__ wgt,
                             u16* __restrict__ wut, u16* __restrict__ wdt,
                             const float* __restrict__ x, u16* __restrict__ xb,
                             const float* __restrict__ gw, float* __restrict__ logits_out,
                             int* __restrict__ te, float* __restrict__ tw) {
  __shared__ float sgw[E_NUM * H_DIM];  // 32 KB (router branch only)
  const int b = blockIdx.x;
  if (b < WCONV_BLOCKS) {
    const int zz = b / (E_NUM * 512);
    const int idx = b - zz * (E_NUM * 512);
    const float* src = (zz == 0) ? Wg : (zz == 1) ? Wu : Wd;
    u16* dst = (zz == 0) ? wgt : (zz == 1) ? wut : wdt;
    const int R = (zz == 2) ? I_DIM : H_DIM;
    const int C = (zz == 2) ? H_DIM : I_DIM;
    const int cpt = C >> 6;
    const int e = idx >> 9;
    const int ti = idx & 511;
    const int r0 = (ti / cpt) << 6;
    const int c0 = (ti % cpt) << 6;
    const float* s = src + (size_t)e * H_DIM * I_DIM;
    u16* d = dst + (size_t)e * H_DIM * I_DIM;

    const int wave = threadIdx.x >> 6, lane = threadIdx.x & 63;
    const int g = lane >> 4, lq = lane & 15;
    const int c = c0 + wave * 16 + g * 4;
    const int r = r0 + lq * 4;

    float4 v0 = *(const float4*)(s + (size_t)(r + 0) * C + c);
    float4 v1 = *(const float4*)(s + (size_t)(r + 1) * C + c);
    float4 v2 = *(const float4*)(s + (size_t)(r + 2) * C + c);
    float4 v3 = *(const float4*)(s + (size_t)(r + 3) * C + c);

    ushort4 o;
    o.x = f2bf(v0.x); o.y = f2bf(v1.x); o.z = f2bf(v2.x); o.w = f2bf(v3.x);
    *(ushort4*)(d + (size_t)(c + 0) * R + r) = o;
    o.x = f2bf(v0.y); o.y = f2bf(v1.y); o.z = f2bf(v2.y); o.w = f2bf(v3.y);
    *(ushort4*)(d + (size_t)(c + 1) * R + r) = o;
    o.x = f2bf(v0.z); o.y = f2bf(v1.z); o.z = f2bf(v2.z); o.w = f2bf(v3.z);
    *(ushort4*)(d + (size_t)(c + 2) * R + r) = o;
    o.x = f2bf(v0.w); o.y = f2bf(v1.w); o.z = f2bf(v2.w); o.w = f2bf(v3.w);
    *(ushort4*)(d + (size_t)(c + 3) * R + r) = o;
  } else {
    const int rb = b - WCONV_BLOCKS;
    // stage gw [H][E] -> sgw [E][H] (L2-resident after first touch)
    for (int j = threadIdx.x; j < (H_DIM * E_NUM) / 4; j += 256) {
      float4 v = ((const float4*)gw)[j];
      int base = j * 4;
      sgw[((base + 0) & 7) * H_DIM + ((base + 0) >> 3)] = v.x;
      sgw[((base + 1) & 7) * H_DIM + ((base + 1) >> 3)] = v.y;
      sgw[((base + 2) & 7) * H_DIM + ((base + 2) >> 3)] = v.z;
      sgw[((base + 3) & 7) * H_DIM + ((base + 3) >> 3)] = v.w;
    }
    __syncthreads();
    const int wave = threadIdx.x >> 6, lane = threadIdx.x & 63;
    const int t = rb * 4 + wave;
    const float* xr = x + (size_t)t * H_DIM;
    u16* xbr = xb + (size_t)t * H_DIM;
    float acc[8];
#pragma unroll
    for (int e = 0; e < 8; e++) acc[e] = 0.f;
#pragma unroll
    for (int it = 0; it < 4; it++) {
      int h0 = it * 256 + lane * 4;
      float4 xv = *(const float4*)(xr + h0);
      ushort4 o;
      o.x = f2bf(xv.x); o.y = f2bf(xv.y); o.z = f2bf(xv.z); o.w = f2bf(xv.w);
      *(ushort4*)(xbr + h0) = o;  // fused x->bf16 conversion
#pragma unroll
      for (int e = 0; e < 8; e++) {
        float4 g = *(const float4*)(&sgw[e * H_DIM + h0]);
        acc[e] += xv.x * g.x + xv.y * g.y + xv.z * g.z + xv.w * g.w;
      }
    }
#pragma unroll
    for (int m = 1; m < 64; m <<= 1) {
#pragma unroll
      for (int e = 0; e < 8; e++) acc[e] += __shfl_xor(acc[e], m, 64);
    }
    if (lane == 0) {
      float mx = acc[0];
#pragma unroll
      for (int e = 1; e < 8; e++) mx = fmaxf(mx, acc[e]);
      float p[8]; float s = 0.f;
#pragma unroll
      for (int e = 0; e < 8; e++) { p[e] = __expf(acc[e] - mx); s += p[e]; }
      float inv = 1.0f / s;
      int e0 = 0; float b0 = acc[0];
#pragma unroll
      for (int e = 1; e < 8; e++) if (acc[e] > b0) { b0 = acc[e]; e0 = e; }
      int e1 = -1; float b1 = -1e30f;
#pragma unroll
      for (int e = 0; e < 8; e++) if (e != e0 && acc[e] > b1) { b1 = acc[e]; e1 = e; }
#pragma unroll
      for (int e = 0; e < 8; e++) logits_out[(size_t)t * 8 + e] = acc[e];
      te[t * 2] = e0; te[t * 2 + 1] = e1;
      tw[t * 2] = p[e0] * inv; tw[t * 2 + 1] = p[e1] * inv;
    }
  }
}

// ---------------- sort: deterministic expert-bucket positions, single block, no atomics --
__global__ __launch_bounds__(1024) void sort_kernel(const int* __restrict__ te,
                                                    int* __restrict__ offs,
                                                    int* __restrict__ token_list,
                                                    int* __restrict__ tpos) {
  __shared__ int wsum[16][8];
  __shared__ int wbase[16][8];
  __shared__ int soffs[9];
  const int tid = threadIdx.x;
  const int wave = tid >> 6, lane = tid & 63;

  for (int j = tid; j < PMAX; j += 1024) token_list[j] = 0;

  const int t0 = tid * 4;
  int e_loc[8];
  int cnt[8];
#pragma unroll
  for (int e = 0; e < 8; e++) cnt[e] = 0;
#pragma unroll
  for (int k = 0; k < 8; k++) {
    int e = te[t0 * 2 + k];
    e_loc[k] = e;
    cnt[e]++;
  }
  int excl[8];
#pragma unroll
  for (int e = 0; e < 8; e++) {
    int v = cnt[e];
    int s = v;
#pragma unroll
    for (int d = 1; d < 64; d <<= 1) {
      int u = __shfl_up(s, d, 64);
      if (lane >= d) s += u;
    }
    excl[e] = s - v;
    if (lane == 63) wsum[wave][e] = s;
  }
  __syncthreads();
  if (tid < 8) {
    int e = tid;
    int a = 0;
    for (int w2 = 0; w2 < 16; w2++) { wbase[w2][e] = a; a += wsum[w2][e]; }
    wsum[0][e] = a;
  }
  __syncthreads();
  if (tid == 0) {
    int a = 0;
    for (int e = 0; e < 8; e++) {
      soffs[e] = a;
      a += (wsum[0][e] + 127) & ~127;
    }
    soffs[8] = a;
    for (int e = 0; e <= 8; e++) offs[e] = soffs[e];
  }
  __syncthreads();
  int base[8];
#pragma unroll
  for (int e = 0; e < 8; e++) base[e] = soffs[e] + wbase[wave][e] + excl[e];
#pragma unroll
  for (int k = 0; k < 8; k++) {
    int e = e_loc[k];
    int pos = base[e]++;
    int t = t0 + (k >> 1);
    token_list[pos] = t;
    tpos[t * 2 + (k & 1)] = pos;
  }
}

// ---------------- GEMM1: mid = silu(Xe @ Wg) * (Xe @ Wu) ----------------
// 128x128 tile, BK=64, xor-swizzled LDS; launch_bounds 3 blocks/CU (48KB LDS * 3 = 144 < 160)
#define BK1 64

__global__ __launch_bounds__(256, 3) void gemm1_kernel(
    const u16* __restrict__ xb, const u16* __restrict__ wgt, const u16* __restrict__ wut,
    const int* __restrict__ token_list, const int* __restrict__ offs, u16* __restrict__ mid) {
  const int e = blockIdx.z;
  const int off = offs[e];
  const int pcount = offs[e + 1] - off;
  const int row0 = blockIdx.y * 128;
  if (row0 >= pcount) return;
  const int n0 = blockIdx.x * 128;

  __shared__ __align__(16) u16 As[128 * BK1];
  __shared__ __align__(16) u16 Bg[128 * BK1];
  __shared__ __align__(16) u16 Bu[128 * BK1];

  const int tid = threadIdx.x;
  const int wave = tid >> 6, lane = tid & 63;
  const int wm = (wave >> 1) * 64, wn = (wave & 1) * 64;
  const int quad = lane >> 4, lr = lane & 15;
  const int l7 = lr & 7;

  f32x4 accg[4][4], accu[4][4];
  f32x4 z = {0.f, 0.f, 0.f, 0.f};
#pragma unroll
  for (int i = 0; i < 4; i++)
#pragma unroll
    for (int j = 0; j < 4; j++) { accg[i][j] = z; accu[i][j] = z; }

  const u16* wgb = wgt + (size_t)e * I_DIM * H_DIM;
  const u16* wub = wut + (size_t)e * I_DIM * H_DIM;

  const u16* ga[4]; const u16* gg[4]; const u16* gu[4];
  u16 *la[4], *lg[4], *lu[4];
#pragma unroll
  for (int i = 0; i < 4; i++) {
    int c = tid + 256 * i;
    int row = c >> 3, kcl = c & 7;
    int kg = kcl ^ (row & 7);
    int tok = token_list[off + row0 + row];  // padded rows -> token 0 (harmless)
    ga[i] = xb + (size_t)tok * H_DIM + kg * 8;
    gg[i] = wgb + (size_t)(n0 + row) * H_DIM + kg * 8;
    gu[i] = wub + (size_t)(n0 + row) * H_DIM + kg * 8;
    la[i] = &As[c * 8]; lg[i] = &Bg[c * 8]; lu[i] = &Bu[c * 8];
  }

  for (int kt = 0; kt < H_DIM / BK1; kt++) {
    const int k0 = kt * BK1;
#pragma unroll
    for (int i = 0; i < 4; i++) {
      async_ld16(ga[i] + k0, la[i]);
      async_ld16(gg[i] + k0, lg[i]);
      async_ld16(gu[i] + k0, lu[i]);
    }
    __syncthreads();
#pragma unroll
    for (int kk = 0; kk < 2; kk++) {
      const int slot = ((kk << 2) + quad) ^ l7;
      short8 af[4];
#pragma unroll
      for (int im = 0; im < 4; im++)
        af[im] = *(const short8*)(&As[(wm + im * 16 + lr) * BK1 + slot * 8]);
#pragma unroll
      for (int in = 0; in < 4; in++) {
        short8 bg = *(const short8*)(&Bg[(wn + in * 16 + lr) * BK1 + slot * 8]);
        short8 bu = *(const short8*)(&Bu[(wn + in * 16 + lr) * BK1 + slot * 8]);
#pragma unroll
        for (int im = 0; im < 4; im++) {
          accg[im][in] = __builtin_amdgcn_mfma_f32_16x16x32_bf16(af[im], bg, accg[im][in], 0, 0, 0);
          accu[im][in] = __builtin_amdgcn_mfma_f32_16x16x32_bf16(af[im], bu, accu[im][in], 0, 0, 0);
        }
      }
    }
    __syncthreads();
  }

#pragma unroll
  for (int im = 0; im < 4; im++) {
#pragma unroll
    for (int r = 0; r < 4; r++) {
      int row = row0 + wm + im * 16 + quad * 4 + r;
      u16* mrow = mid + (size_t)(off + row) * I_DIM + n0 + wn;
#pragma unroll
      for (int in = 0; in < 4; in++) {
        float g = accg[im][in][r];
        float u = accu[im][in][r];
        float sv = g / (1.0f + __expf(-g)) * u;  // silu(g) * u
        mrow[in * 16 + lr] = f2bf(sv);
      }
    }
  }
}

// ---------------- GEMM2: eout = mid @ Wd^T  (dense bf16 store, no atomics) ----------------
// 32KB LDS -> 4 blocks/CU
__global__ __launch_bounds__(256, 4) void gemm2_kernel(
    const u16* __restrict__ mid, const u16* __restrict__ wdt,
    const int* __restrict__ offs, u16* __restrict__ eout) {
  const int e = blockIdx.z;
  const int off = offs[e];
  const int pcount = offs[e + 1] - off;
  const int row0 = blockIdx.y * 128;
  if (row0 >= pcount) return;
  const int n0 = blockIdx.x * 128;

  __shared__ __align__(16) u16 As[128 * BK1];
  __shared__ __align__(16) u16 Bs[128 * BK1];

  const int tid = threadIdx.x;
  const int wave = tid >> 6, lane = tid & 63;
  const int wm = (wave >> 1) * 64, wn = (wave & 1) * 64;
  const int quad = lane >> 4, lr = lane & 15;
  const int l7 = lr & 7;

  f32x4 acc[4][4];
  f32x4 z = {0.f, 0.f, 0.f, 0.f};
#pragma unroll
  for (int i = 0; i < 4; i++)
#pragma unroll
    for (int j = 0; j < 4; j++) acc[i][j] = z;

  const u16* wdb = wdt + (size_t)e * H_DIM * I_DIM;

  const u16* ga[4]; const u16* gb[4];
  u16 *la[4], *lb[4];
#pragma unroll
  for (int i = 0; i < 4; i++) {
    int c = tid + 256 * i;
    int row = c >> 3, kcl = c & 7;
    int kg = kcl ^ (row & 7);
    ga[i] = mid + (size_t)(off + row0 + row) * I_DIM + kg * 8;
    gb[i] = wdb + (size_t)(n0 + row) * I_DIM + kg * 8;
    la[i] = &As[c * 8]; lb[i] = &Bs[c * 8];
  }

  for (int kt = 0; kt < I_DIM / BK1; kt++) {
    const int k0 = kt * BK1;
#pragma unroll
    for (int i = 0; i < 4; i++) {
      async_ld16(ga[i] + k0, la[i]);
      async_ld16(gb[i] + k0, lb[i]);
    }
    __syncthreads();
#pragma unroll
    for (int kk = 0; kk < 2; kk++) {
      const int slot = ((kk << 2) + quad) ^ l7;
      short8 af[4];
#pragma unroll
      for (int im = 0; im < 4; im++)
        af[im] = *(const short8*)(&As[(wm + im * 16 + lr) * BK1 + slot * 8]);
#pragma unroll
      for (int in = 0; in < 4; in++) {
        short8 bf = *(const short8*)(&Bs[(wn + in * 16 + lr) * BK1 + slot * 8]);
#pragma unroll
        for (int im = 0; im < 4; im++)
          acc[im][in] = __builtin_amdgcn_mfma_f32_16x16x32_bf16(af[im], bf, acc[im][in], 0, 0, 0);
      }
    }
    __syncthreads();
  }

#pragma unroll
  for (int im = 0; im < 4; im++) {
#pragma unroll
    for (int r = 0; r < 4; r++) {
      int row = row0 + wm + im * 16 + quad * 4 + r;
      u16* orow = eout + (size_t)(off + row) * H_DIM + n0 + wn;
#pragma unroll
      for (int in = 0; in < 4; in++)
        orow[in * 16 + lr] = f2bf(acc[im][in][r]);
    }
  }
}

// ---------------- combine: out[t] = w0*eout[p0] + w1*eout[p1] ----------------
__global__ void combine_kernel(const u16* __restrict__ eout, const int* __restrict__ tpos,
                               const float* __restrict__ tw, float* __restrict__ out) {
  const int half = threadIdx.x >> 7;
  const int t = blockIdx.x * 2 + half;
  const int lt = threadIdx.x & 127;
  const int h0 = lt * 8;
  const int p0 = tpos[t * 2], p1 = tpos[t * 2 + 1];
  const float w0 = tw[t * 2], w1 = tw[t * 2 + 1];
  ushort4 a0 = *(const ushort4*)(eout + (size_t)p0 * H_DIM + h0);
  ushort4 a1 = *(const ushort4*)(eout + (size_t)p0 * H_DIM + h0 + 4);
  ushort4 b0 = *(const ushort4*)(eout + (size_t)p1 * H_DIM + h0);
  ushort4 b1 = *(const ushort4*)(eout + (size_t)p1 * H_DIM + h0 + 4);
  float4 o0, o1;
  o0.x = w0 * bf2f(a0.x) + w1 * bf2f(b0.x);
  o0.y = w0 * bf2f(a0.y) + w1 * bf2f(b0.y);
  o0.z = w0 * bf2f(a0.z) + w1 * bf2f(b0.z);
  o0.w = w0 * bf2f(a0.w) + w1 * bf2f(b0.w);
  o1.x = w0 * bf2f(a1.x) + w1 * bf2f(b1.x);
  o1.y = w0 * bf2f(a1.y) + w1 * bf2f(b1.y);
  o1.z = w0 * bf2f(a1.z) + w1 * bf2f(b1.z);
  o1.w = w0 * bf2f(a1.w) + w1 * bf2f(b1.w);
  float* orow = out + (size_t)t * H_DIM + h0;
  *(float4*)(orow) = o0;
  *(float4*)(orow + 4) = o1;
}

// ---------------- launch ----------------
extern "C" void kernel_launch(void* const* d_in, const int* in_sizes, int n_in,
                              void* d_out, int out_size, void* d_ws, size_t ws_size,
                              hipStream_t stream) {
  const float* x  = (const float*)d_in[0];   // [T, H]
  const float* gw = (const float*)d_in[1];   // [H, E]
  const float* Wg = (const float*)d_in[2];   // [E, H, I]
  const float* Wu = (const float*)d_in[3];   // [E, H, I]
  const float* Wd = (const float*)d_in[4];   // [E, I, H]
  float* out = (float*)d_out;                          // [T, H]
  float* out_logits = out + (size_t)T_TOK * H_DIM;     // [T, E]

  char* w = (char*)d_ws;
  size_t o = 0;
  auto take = [&](size_t bytes) { char* p = w + o; o += (bytes + 255) & ~(size_t)255; return p; };
  int*   offs        = (int*)take((E_NUM + 1) * 4);
  int*   te          = (int*)take((size_t)T_TOK * 2 * 4);
  float* tw          = (float*)take((size_t)T_TOK * 2 * 4);
  int*   token_list  = (int*)take((size_t)PMAX * 4);
  int*   tpos        = (int*)take((size_t)T_TOK * 2 * 4);
  u16*   xb          = (u16*)take((size_t)T_TOK * H_DIM * 2);
  u16*   wgt         = (u16*)take((size_t)E_NUM * H_DIM * I_DIM * 2);  // [E][I][H] bf16
  u16*   wut         = (u16*)take((size_t)E_NUM * H_DIM * I_DIM * 2);  // [E][I][H] bf16
  u16*   wdt         = (u16*)take((size_t)E_NUM * H_DIM * I_DIM * 2);  // [E][H][I] bf16
  u16*   mid         = (u16*)take((size_t)PMAX * I_DIM * 2);           // [PMAX][I] bf16
  // eout aliases wgt: gemm1 (last reader of wgt) completes before gemm2 writes eout
  u16*   eout        = wgt;                                            // [PMAX][H] bf16
  (void)in_sizes; (void)n_in; (void)out_size; (void)ws_size;

  front_kernel<<<WCONV_BLOCKS + ROUTER_BLOCKS, 256, 0, stream>>>(
      Wg, Wu, Wd, wgt, wut, wdt, x, xb, gw, out_logits, te, tw);
  sort_kernel<<<1, 1024, 0, stream>>>(te, offs, token_list, tpos);
  gemm1_kernel<<<dim3(I_DIM / 128, PMAX / 128, E_NUM), 256, 0, stream>>>(xb, wgt, wut, token_list, offs, mid);
  gemm2_kernel<<<dim3(H_DIM / 128, PMAX / 128, E_NUM), 256, 0, stream>>>(mid, wdt, offs, eout);
  combine_kernel<<<T_TOK / 2, 256, 0, stream>>>(eout, tpos, tw, out);
}

// Round 7
// 406.288 us; speedup vs baseline: 1.1867x; 1.1867x over previous
//
#include <hip/hip_runtime.h>
#include <stdint.h>
#include <math.h>

#define T_TOK 4096
#define H_DIM 1024
#define I_DIM 2048
#define E_NUM 8
#define PMAX (T_TOK * 2 + E_NUM * 128)  // 9216 padded dispatch rows upper bound

#define WCONV_BLOCKS (E_NUM * 512 * 3)  // 12288
#define ROUTER_BLOCKS (T_TOK / 4)       // 1024

typedef __attribute__((ext_vector_type(8))) short short8;
typedef __attribute__((ext_vector_type(4))) float f32x4;
typedef unsigned short u16;
typedef unsigned int u32;

__device__ __forceinline__ u16 f2bf(float f) {
  union { float f; u32 u; } v; v.f = f;
  u32 r = v.u + 0x7fffu + ((v.u >> 16) & 1u);  // round-to-nearest-even
  return (u16)(r >> 16);
}
__device__ __forceinline__ float bf2f(u16 a) {
  union { u32 u; float f; } v; v.u = ((u32)a) << 16; return v.f;
}

// async global->LDS DMA, 16 B per lane (m97 pattern; dest = wave base + lane*16)
__device__ __forceinline__ void async_ld16(const u16* g, u16* l) {
  __builtin_amdgcn_global_load_lds(
      (const __attribute__((address_space(1))) void*)g,
      (__attribute__((address_space(3))) void*)l, 16, 0, 0);
}

// ---------------- front: wconv (12288 blocks) + router/xcvt (1024 blocks) ----------------
__global__ void front_kernel(const float* __restrict__ Wg, const float* __restrict__ Wu,
                             const float* __restrict__ Wd, u16* __restrict__ wgt,
                             u16* __restrict__ wut, u16* __restrict__ wdt,
                             const float* __restrict__ x, u16* __restrict__ xb,
                             const float* __restrict__ gw, float* __restrict__ logits_out,
                             int* __restrict__ te, float* __restrict__ tw) {
  __shared__ float sgw[E_NUM * H_DIM];  // 32 KB (router branch only)
  const int b = blockIdx.x;
  if (b < WCONV_BLOCKS) {
    const int zz = b / (E_NUM * 512);
    const int idx = b - zz * (E_NUM * 512);
    const float* src = (zz == 0) ? Wg : (zz == 1) ? Wu : Wd;
    u16* dst = (zz == 0) ? wgt : (zz == 1) ? wut : wdt;
    const int R = (zz == 2) ? I_DIM : H_DIM;
    const int C = (zz == 2) ? H_DIM : I_DIM;
    const int cpt = C >> 6;
    const int e = idx >> 9;
    const int ti = idx & 511;
    const int r0 = (ti / cpt) << 6;
    const int c0 = (ti % cpt) << 6;
    const float* s = src + (size_t)e * H_DIM * I_DIM;
    u16* d = dst + (size_t)e * H_DIM * I_DIM;

    const int wave = threadIdx.x >> 6, lane = threadIdx.x & 63;
    const int g = lane >> 4, lq = lane & 15;
    const int c = c0 + wave * 16 + g * 4;
    const int r = r0 + lq * 4;

    float4 v0 = *(const float4*)(s + (size_t)(r + 0) * C + c);
    float4 v1 = *(const float4*)(s + (size_t)(r + 1) * C + c);
    float4 v2 = *(const float4*)(s + (size_t)(r + 2) * C + c);
    float4 v3 = *(const float4*)(s + (size_t)(r + 3) * C + c);

    ushort4 o;
    o.x = f2bf(v0.x); o.y = f2bf(v1.x); o.z = f2bf(v2.x); o.w = f2bf(v3.x);
    *(ushort4*)(d + (size_t)(c + 0) * R + r) = o;
    o.x = f2bf(v0.y); o.y = f2bf(v1.y); o.z = f2bf(v2.y); o.w = f2bf(v3.y);
    *(ushort4*)(d + (size_t)(c + 1) * R + r) = o;
    o.x = f2bf(v0.z); o.y = f2bf(v1.z); o.z = f2bf(v2.z); o.w = f2bf(v3.z);
    *(ushort4*)(d + (size_t)(c + 2) * R + r) = o;
    o.x = f2bf(v0.w); o.y = f2bf(v1.w); o.z = f2bf(v2.w); o.w = f2bf(v3.w);
    *(ushort4*)(d + (size_t)(c + 3) * R + r) = o;
  } else {
    const int rb = b - WCONV_BLOCKS;
    // stage gw [H][E] -> sgw [E][H]
    for (int j = threadIdx.x; j < (H_DIM * E_NUM) / 4; j += 256) {
      float4 v = ((const float4*)gw)[j];
      int base = j * 4;
      sgw[((base + 0) & 7) * H_DIM + ((base + 0) >> 3)] = v.x;
      sgw[((base + 1) & 7) * H_DIM + ((base + 1) >> 3)] = v.y;
      sgw[((base + 2) & 7) * H_DIM + ((base + 2) >> 3)] = v.z;
      sgw[((base + 3) & 7) * H_DIM + ((base + 3) >> 3)] = v.w;
    }
    __syncthreads();
    const int wave = threadIdx.x >> 6, lane = threadIdx.x & 63;
    const int t = rb * 4 + wave;
    const float* xr = x + (size_t)t * H_DIM;
    u16* xbr = xb + (size_t)t * H_DIM;
    float acc[8];
#pragma unroll
    for (int e = 0; e < 8; e++) acc[e] = 0.f;
#pragma unroll
    for (int it = 0; it < 4; it++) {
      int h0 = it * 256 + lane * 4;
      float4 xv = *(const float4*)(xr + h0);
      ushort4 o;
      o.x = f2bf(xv.x); o.y = f2bf(xv.y); o.z = f2bf(xv.z); o.w = f2bf(xv.w);
      *(ushort4*)(xbr + h0) = o;  // fused x->bf16 conversion
#pragma unroll
      for (int e = 0; e < 8; e++) {
        float4 g = *(const float4*)(&sgw[e * H_DIM + h0]);
        acc[e] += xv.x * g.x + xv.y * g.y + xv.z * g.z + xv.w * g.w;
      }
    }
#pragma unroll
    for (int m = 1; m < 64; m <<= 1) {
#pragma unroll
      for (int e = 0; e < 8; e++) acc[e] += __shfl_xor(acc[e], m, 64);
    }
    if (lane == 0) {
      float mx = acc[0];
#pragma unroll
      for (int e = 1; e < 8; e++) mx = fmaxf(mx, acc[e]);
      float p[8]; float s = 0.f;
#pragma unroll
      for (int e = 0; e < 8; e++) { p[e] = __expf(acc[e] - mx); s += p[e]; }
      float inv = 1.0f / s;
      int e0 = 0; float b0 = acc[0];
#pragma unroll
      for (int e = 1; e < 8; e++) if (acc[e] > b0) { b0 = acc[e]; e0 = e; }
      int e1 = -1; float b1 = -1e30f;
#pragma unroll
      for (int e = 0; e < 8; e++) if (e != e0 && acc[e] > b1) { b1 = acc[e]; e1 = e; }
#pragma unroll
      for (int e = 0; e < 8; e++) logits_out[(size_t)t * 8 + e] = acc[e];
      te[t * 2] = e0; te[t * 2 + 1] = e1;
      tw[t * 2] = p[e0] * inv; tw[t * 2 + 1] = p[e1] * inv;
    }
  }
}

// ---------------- sort: deterministic expert-bucket positions, single block, no atomics --
__global__ __launch_bounds__(1024) void sort_kernel(const int* __restrict__ te,
                                                    int* __restrict__ offs,
                                                    int* __restrict__ token_list,
                                                    int* __restrict__ tpos) {
  __shared__ int wsum[16][8];
  __shared__ int wbase[16][8];
  __shared__ int soffs[9];
  const int tid = threadIdx.x;
  const int wave = tid >> 6, lane = tid & 63;

  for (int j = tid; j < PMAX; j += 1024) token_list[j] = 0;

  const int t0 = tid * 4;
  int e_loc[8];
  int cnt[8];
#pragma unroll
  for (int e = 0; e < 8; e++) cnt[e] = 0;
#pragma unroll
  for (int k = 0; k < 8; k++) {
    int e = te[t0 * 2 + k];
    e_loc[k] = e;
    cnt[e]++;
  }
  int excl[8];
#pragma unroll
  for (int e = 0; e < 8; e++) {
    int v = cnt[e];
    int s = v;
#pragma unroll
    for (int d = 1; d < 64; d <<= 1) {
      int u = __shfl_up(s, d, 64);
      if (lane >= d) s += u;
    }
    excl[e] = s - v;
    if (lane == 63) wsum[wave][e] = s;
  }
  __syncthreads();
  if (tid < 8) {
    int e = tid;
    int a = 0;
    for (int w2 = 0; w2 < 16; w2++) { wbase[w2][e] = a; a += wsum[w2][e]; }
    wsum[0][e] = a;
  }
  __syncthreads();
  if (tid == 0) {
    int a = 0;
    for (int e = 0; e < 8; e++) {
      soffs[e] = a;
      a += (wsum[0][e] + 127) & ~127;
    }
    soffs[8] = a;
    for (int e = 0; e <= 8; e++) offs[e] = soffs[e];
  }
  __syncthreads();
  int base[8];
#pragma unroll
  for (int e = 0; e < 8; e++) base[e] = soffs[e] + wbase[wave][e] + excl[e];
#pragma unroll
  for (int k = 0; k < 8; k++) {
    int e = e_loc[k];
    int pos = base[e]++;
    int t = t0 + (k >> 1);
    token_list[pos] = t;
    tpos[t * 2 + (k & 1)] = pos;
  }
}

// ---------------- GEMM1: mid = silu(Xe @ Wg) * (Xe @ Wu) ----------------
// 128x128 tile, BK=64, xor-swizzled LDS.
// launch_bounds(256,2): unified VGPR+AGPR need ~232/wave -> 2 blocks/CU max; (256,3) spills (R6).
#define BK1 64

__global__ __launch_bounds__(256, 2) void gemm1_kernel(
    const u16* __restrict__ xb, const u16* __restrict__ wgt, const u16* __restrict__ wut,
    const int* __restrict__ token_list, const int* __restrict__ offs, u16* __restrict__ mid) {
  const int e = blockIdx.z;
  const int off = offs[e];
  const int pcount = offs[e + 1] - off;
  const int row0 = blockIdx.y * 128;
  if (row0 >= pcount) return;
  const int n0 = blockIdx.x * 128;

  __shared__ __align__(16) u16 As[128 * BK1];
  __shared__ __align__(16) u16 Bg[128 * BK1];
  __shared__ __align__(16) u16 Bu[128 * BK1];

  const int tid = threadIdx.x;
  const int wave = tid >> 6, lane = tid & 63;
  const int wm = (wave >> 1) * 64, wn = (wave & 1) * 64;
  const int quad = lane >> 4, lr = lane & 15;
  const int l7 = lr & 7;

  f32x4 accg[4][4], accu[4][4];
  f32x4 z = {0.f, 0.f, 0.f, 0.f};
#pragma unroll
  for (int i = 0; i < 4; i++)
#pragma unroll
    for (int j = 0; j < 4; j++) { accg[i][j] = z; accu[i][j] = z; }

  const u16* wgb = wgt + (size_t)e * I_DIM * H_DIM;
  const u16* wub = wut + (size_t)e * I_DIM * H_DIM;

  const u16* ga[4]; const u16* gg[4]; const u16* gu[4];
  u16 *la[4], *lg[4], *lu[4];
#pragma unroll
  for (int i = 0; i < 4; i++) {
    int c = tid + 256 * i;
    int row = c >> 3, kcl = c & 7;
    int kg = kcl ^ (row & 7);
    int tok = token_list[off + row0 + row];  // padded rows -> token 0 (harmless)
    ga[i] = xb + (size_t)tok * H_DIM + kg * 8;
    gg[i] = wgb + (size_t)(n0 + row) * H_DIM + kg * 8;
    gu[i] = wub + (size_t)(n0 + row) * H_DIM + kg * 8;
    la[i] = &As[c * 8]; lg[i] = &Bg[c * 8]; lu[i] = &Bu[c * 8];
  }

  for (int kt = 0; kt < H_DIM / BK1; kt++) {
    const int k0 = kt * BK1;
#pragma unroll
    for (int i = 0; i < 4; i++) {
      async_ld16(ga[i] + k0, la[i]);
      async_ld16(gg[i] + k0, lg[i]);
      async_ld16(gu[i] + k0, lu[i]);
    }
    __syncthreads();
#pragma unroll
    for (int kk = 0; kk < 2; kk++) {
      const int slot = ((kk << 2) + quad) ^ l7;
      short8 af[4];
#pragma unroll
      for (int im = 0; im < 4; im++)
        af[im] = *(const short8*)(&As[(wm + im * 16 + lr) * BK1 + slot * 8]);
#pragma unroll
      for (int in = 0; in < 4; in++) {
        short8 bg = *(const short8*)(&Bg[(wn + in * 16 + lr) * BK1 + slot * 8]);
        short8 bu = *(const short8*)(&Bu[(wn + in * 16 + lr) * BK1 + slot * 8]);
#pragma unroll
        for (int im = 0; im < 4; im++) {
          accg[im][in] = __builtin_amdgcn_mfma_f32_16x16x32_bf16(af[im], bg, accg[im][in], 0, 0, 0);
          accu[im][in] = __builtin_amdgcn_mfma_f32_16x16x32_bf16(af[im], bu, accu[im][in], 0, 0, 0);
        }
      }
    }
    __syncthreads();
  }

#pragma unroll
  for (int im = 0; im < 4; im++) {
#pragma unroll
    for (int r = 0; r < 4; r++) {
      int row = row0 + wm + im * 16 + quad * 4 + r;
      u16* mrow = mid + (size_t)(off + row) * I_DIM + n0 + wn;
#pragma unroll
      for (int in = 0; in < 4; in++) {
        float g = accg[im][in][r];
        float u = accu[im][in][r];
        float sv = g / (1.0f + __expf(-g)) * u;  // silu(g) * u
        mrow[in * 16 + lr] = f2bf(sv);
      }
    }
  }
}

// ---------------- GEMM2: eout = mid @ Wd^T  (dense bf16 store, no atomics) ----------------
__global__ __launch_bounds__(256, 2) void gemm2_kernel(
    const u16* __restrict__ mid, const u16* __restrict__ wdt,
    const int* __restrict__ offs, u16* __restrict__ eout) {
  const int e = blockIdx.z;
  const int off = offs[e];
  const int pcount = offs[e + 1] - off;
  const int row0 = blockIdx.y * 128;
  if (row0 >= pcount) return;
  const int n0 = blockIdx.x * 128;

  __shared__ __align__(16) u16 As[128 * BK1];
  __shared__ __align__(16) u16 Bs[128 * BK1];

  const int tid = threadIdx.x;
  const int wave = tid >> 6, lane = tid & 63;
  const int wm = (wave >> 1) * 64, wn = (wave & 1) * 64;
  const int quad = lane >> 4, lr = lane & 15;
  const int l7 = lr & 7;

  f32x4 acc[4][4];
  f32x4 z = {0.f, 0.f, 0.f, 0.f};
#pragma unroll
  for (int i = 0; i < 4; i++)
#pragma unroll
    for (int j = 0; j < 4; j++) acc[i][j] = z;

  const u16* wdb = wdt + (size_t)e * H_DIM * I_DIM;

  const u16* ga[4]; const u16* gb[4];
  u16 *la[4], *lb[4];
#pragma unroll
  for (int i = 0; i < 4; i++) {
    int c = tid + 256 * i;
    int row = c >> 3, kcl = c & 7;
    int kg = kcl ^ (row & 7);
    ga[i] = mid + (size_t)(off + row0 + row) * I_DIM + kg * 8;
    gb[i] = wdb + (size_t)(n0 + row) * I_DIM + kg * 8;
    la[i] = &As[c * 8]; lb[i] = &Bs[c * 8];
  }

  for (int kt = 0; kt < I_DIM / BK1; kt++) {
    const int k0 = kt * BK1;
#pragma unroll
    for (int i = 0; i < 4; i++) {
      async_ld16(ga[i] + k0, la[i]);
      async_ld16(gb[i] + k0, lb[i]);
    }
    __syncthreads();
#pragma unroll
    for (int kk = 0; kk < 2; kk++) {
      const int slot = ((kk << 2) + quad) ^ l7;
      short8 af[4];
#pragma unroll
      for (int im = 0; im < 4; im++)
        af[im] = *(const short8*)(&As[(wm + im * 16 + lr) * BK1 + slot * 8]);
#pragma unroll
      for (int in = 0; in < 4; in++) {
        short8 bf = *(const short8*)(&Bs[(wn + in * 16 + lr) * BK1 + slot * 8]);
#pragma unroll
        for (int im = 0; im < 4; im++)
          acc[im][in] = __builtin_amdgcn_mfma_f32_16x16x32_bf16(af[im], bf, acc[im][in], 0, 0, 0);
      }
    }
    __syncthreads();
  }

#pragma unroll
  for (int im = 0; im < 4; im++) {
#pragma unroll
    for (int r = 0; r < 4; r++) {
      int row = row0 + wm + im * 16 + quad * 4 + r;
      u16* orow = eout + (size_t)(off + row) * H_DIM + n0 + wn;
#pragma unroll
      for (int in = 0; in < 4; in++)
        orow[in * 16 + lr] = f2bf(acc[im][in][r]);
    }
  }
}

// ---------------- combine: out[t] = w0*eout[p0] + w1*eout[p1] ----------------
__global__ void combine_kernel(const u16* __restrict__ eout, const int* __restrict__ tpos,
                               const float* __restrict__ tw, float* __restrict__ out) {
  const int half = threadIdx.x >> 7;
  const int t = blockIdx.x * 2 + half;
  const int lt = threadIdx.x & 127;
  const int h0 = lt * 8;
  const int p0 = tpos[t * 2], p1 = tpos[t * 2 + 1];
  const float w0 = tw[t * 2], w1 = tw[t * 2 + 1];
  ushort4 a0 = *(const ushort4*)(eout + (size_t)p0 * H_DIM + h0);
  ushort4 a1 = *(const ushort4*)(eout + (size_t)p0 * H_DIM + h0 + 4);
  ushort4 b0 = *(const ushort4*)(eout + (size_t)p1 * H_DIM + h0);
  ushort4 b1 = *(const ushort4*)(eout + (size_t)p1 * H_DIM + h0 + 4);
  float4 o0, o1;
  o0.x = w0 * bf2f(a0.x) + w1 * bf2f(b0.x);
  o0.y = w0 * bf2f(a0.y) + w1 * bf2f(b0.y);
  o0.z = w0 * bf2f(a0.z) + w1 * bf2f(b0.z);
  o0.w = w0 * bf2f(a0.w) + w1 * bf2f(b0.w);
  o1.x = w0 * bf2f(a1.x) + w1 * bf2f(b1.x);
  o1.y = w0 * bf2f(a1.y) + w1 * bf2f(b1.y);
  o1.z = w0 * bf2f(a1.z) + w1 * bf2f(b1.z);
  o1.w = w0 * bf2f(a1.w) + w1 * bf2f(b1.w);
  float* orow = out + (size_t)t * H_DIM + h0;
  *(float4*)(orow) = o0;
  *(float4*)(orow + 4) = o1;
}

// ---------------- launch ----------------
extern "C" void kernel_launch(void* const* d_in, const int* in_sizes, int n_in,
                              void* d_out, int out_size, void* d_ws, size_t ws_size,
                              hipStream_t stream) {
  const float* x  = (const float*)d_in[0];   // [T, H]
  const float* gw = (const float*)d_in[1];   // [H, E]
  const float* Wg = (const float*)d_in[2];   // [E, H, I]
  const float* Wu = (const float*)d_in[3];   // [E, H, I]
  const float* Wd = (const float*)d_in[4];   // [E, I, H]
  float* out = (float*)d_out;                          // [T, H]
  float* out_logits = out + (size_t)T_TOK * H_DIM;     // [T, E]

  char* w = (char*)d_ws;
  size_t o = 0;
  auto take = [&](size_t bytes) { char* p = w + o; o += (bytes + 255) & ~(size_t)255; return p; };
  int*   offs        = (int*)take((E_NUM + 1) * 4);
  int*   te          = (int*)take((size_t)T_TOK * 2 * 4);
  float* tw          = (float*)take((size_t)T_TOK * 2 * 4);
  int*   token_list  = (int*)take((size_t)PMAX * 4);
  int*   tpos        = (int*)take((size_t)T_TOK * 2 * 4);
  u16*   xb          = (u16*)take((size_t)T_TOK * H_DIM * 2);
  u16*   wgt         = (u16*)take((size_t)E_NUM * H_DIM * I_DIM * 2);  // [E][I][H] bf16
  u16*   wut         = (u16*)take((size_t)E_NUM * H_DIM * I_DIM * 2);  // [E][I][H] bf16
  u16*   wdt         = (u16*)take((size_t)E_NUM * H_DIM * I_DIM * 2);  // [E][H][I] bf16
  u16*   mid         = (u16*)take((size_t)PMAX * I_DIM * 2);           // [PMAX][I] bf16
  // eout aliases wgt: gemm1 (last reader of wgt) completes before gemm2 writes eout
  u16*   eout        = wgt;                                            // [PMAX][H] bf16
  (void)in_sizes; (void)n_in; (void)out_size; (void)ws_size;

  front_kernel<<<WCONV_BLOCKS + ROUTER_BLOCKS, 256, 0, stream>>>(
      Wg, Wu, Wd, wgt, wut, wdt, x, xb, gw, out_logits, te, tw);
  sort_kernel<<<1, 1024, 0, stream>>>(te, offs, token_list, tpos);
  gemm1_kernel<<<dim3(I_DIM / 128, PMAX / 128, E_NUM), 256, 0, stream>>>(xb, wgt, wut, token_list, offs, mid);
  gemm2_kernel<<<dim3(H_DIM / 128, PMAX / 128, E_NUM), 256, 0, stream>>>(mid, wdt, offs, eout);
  combine_kernel<<<T_TOK / 2, 256, 0, stream>>>(eout, tpos, tw, out);
}

// Round 8
// 406.274 us; speedup vs baseline: 1.1867x; 1.0000x over previous
//
#include <hip/hip_runtime.h>
#include <stdint.h>
#include <math.h>

#define T_TOK 4096
#define H_DIM 1024
#define I_DIM 2048
#define E_NUM 8
#define PMAX (T_TOK * 2 + E_NUM * 128)  // 9216 padded dispatch rows upper bound

#define WCONV_BLOCKS (E_NUM * 512 * 3)  // 12288
#define ROUTER_BLOCKS (T_TOK / 4)       // 1024

typedef __attribute__((ext_vector_type(8))) short short8;
typedef __attribute__((ext_vector_type(16))) float f32x16;
typedef unsigned short u16;
typedef unsigned int u32;

__device__ __forceinline__ u16 f2bf(float f) {
  union { float f; u32 u; } v; v.f = f;
  u32 r = v.u + 0x7fffu + ((v.u >> 16) & 1u);  // round-to-nearest-even
  return (u16)(r >> 16);
}
__device__ __forceinline__ float bf2f(u16 a) {
  union { u32 u; float f; } v; v.u = ((u32)a) << 16; return v.f;
}

// async global->LDS DMA, 16 B per lane (m97 pattern; dest = wave base + lane*16)
__device__ __forceinline__ void async_ld16(const u16* g, u16* l) {
  __builtin_amdgcn_global_load_lds(
      (const __attribute__((address_space(1))) void*)g,
      (__attribute__((address_space(3))) void*)l, 16, 0, 0);
}

// ---------------- front: wconv (12288 blocks) + router/xcvt (1024 blocks) ----------------
__global__ void front_kernel(const float* __restrict__ Wg, const float* __restrict__ Wu,
                             const float* __restrict__ Wd, u16* __restrict__ wgt,
                             u16* __restrict__ wut, u16* __restrict__ wdt,
                             const float* __restrict__ x, u16* __restrict__ xb,
                             const float* __restrict__ gw, float* __restrict__ logits_out,
                             int* __restrict__ te, float* __restrict__ tw) {
  __shared__ float sgw[E_NUM * H_DIM];  // 32 KB (router branch only)
  const int b = blockIdx.x;
  if (b < WCONV_BLOCKS) {
    const int zz = b / (E_NUM * 512);
    const int idx = b - zz * (E_NUM * 512);
    const float* src = (zz == 0) ? Wg : (zz == 1) ? Wu : Wd;
    u16* dst = (zz == 0) ? wgt : (zz == 1) ? wut : wdt;
    const int R = (zz == 2) ? I_DIM : H_DIM;
    const int C = (zz == 2) ? H_DIM : I_DIM;
    const int cpt = C >> 6;
    const int e = idx >> 9;
    const int ti = idx & 511;
    const int r0 = (ti / cpt) << 6;
    const int c0 = (ti % cpt) << 6;
    const float* s = src + (size_t)e * H_DIM * I_DIM;
    u16* d = dst + (size_t)e * H_DIM * I_DIM;

    const int wave = threadIdx.x >> 6, lane = threadIdx.x & 63;
    const int g = lane >> 4, lq = lane & 15;
    const int c = c0 + wave * 16 + g * 4;
    const int r = r0 + lq * 4;

    float4 v0 = *(const float4*)(s + (size_t)(r + 0) * C + c);
    float4 v1 = *(const float4*)(s + (size_t)(r + 1) * C + c);
    float4 v2 = *(const float4*)(s + (size_t)(r + 2) * C + c);
    float4 v3 = *(const float4*)(s + (size_t)(r + 3) * C + c);

    ushort4 o;
    o.x = f2bf(v0.x); o.y = f2bf(v1.x); o.z = f2bf(v2.x); o.w = f2bf(v3.x);
    *(ushort4*)(d + (size_t)(c + 0) * R + r) = o;
    o.x = f2bf(v0.y); o.y = f2bf(v1.y); o.z = f2bf(v2.y); o.w = f2bf(v3.y);
    *(ushort4*)(d + (size_t)(c + 1) * R + r) = o;
    o.x = f2bf(v0.z); o.y = f2bf(v1.z); o.z = f2bf(v2.z); o.w = f2bf(v3.z);
    *(ushort4*)(d + (size_t)(c + 2) * R + r) = o;
    o.x = f2bf(v0.w); o.y = f2bf(v1.w); o.z = f2bf(v2.w); o.w = f2bf(v3.w);
    *(ushort4*)(d + (size_t)(c + 3) * R + r) = o;
  } else {
    const int rb = b - WCONV_BLOCKS;
    for (int j = threadIdx.x; j < (H_DIM * E_NUM) / 4; j += 256) {
      float4 v = ((const float4*)gw)[j];
      int base = j * 4;
      sgw[((base + 0) & 7) * H_DIM + ((base + 0) >> 3)] = v.x;
      sgw[((base + 1) & 7) * H_DIM + ((base + 1) >> 3)] = v.y;
      sgw[((base + 2) & 7) * H_DIM + ((base + 2) >> 3)] = v.z;
      sgw[((base + 3) & 7) * H_DIM + ((base + 3) >> 3)] = v.w;
    }
    __syncthreads();
    const int wave = threadIdx.x >> 6, lane = threadIdx.x & 63;
    const int t = rb * 4 + wave;
    const float* xr = x + (size_t)t * H_DIM;
    u16* xbr = xb + (size_t)t * H_DIM;
    float acc[8];
#pragma unroll
    for (int e = 0; e < 8; e++) acc[e] = 0.f;
#pragma unroll
    for (int it = 0; it < 4; it++) {
      int h0 = it * 256 + lane * 4;
      float4 xv = *(const float4*)(xr + h0);
      ushort4 o;
      o.x = f2bf(xv.x); o.y = f2bf(xv.y); o.z = f2bf(xv.z); o.w = f2bf(xv.w);
      *(ushort4*)(xbr + h0) = o;
#pragma unroll
      for (int e = 0; e < 8; e++) {
        float4 g = *(const float4*)(&sgw[e * H_DIM + h0]);
        acc[e] += xv.x * g.x + xv.y * g.y + xv.z * g.z + xv.w * g.w;
      }
    }
#pragma unroll
    for (int m = 1; m < 64; m <<= 1) {
#pragma unroll
      for (int e = 0; e < 8; e++) acc[e] += __shfl_xor(acc[e], m, 64);
    }
    if (lane == 0) {
      float mx = acc[0];
#pragma unroll
      for (int e = 1; e < 8; e++) mx = fmaxf(mx, acc[e]);
      float p[8]; float s = 0.f;
#pragma unroll
      for (int e = 0; e < 8; e++) { p[e] = __expf(acc[e] - mx); s += p[e]; }
      float inv = 1.0f / s;
      int e0 = 0; float b0 = acc[0];
#pragma unroll
      for (int e = 1; e < 8; e++) if (acc[e] > b0) { b0 = acc[e]; e0 = e; }
      int e1 = -1; float b1 = -1e30f;
#pragma unroll
      for (int e = 0; e < 8; e++) if (e != e0 && acc[e] > b1) { b1 = acc[e]; e1 = e; }
#pragma unroll
      for (int e = 0; e < 8; e++) logits_out[(size_t)t * 8 + e] = acc[e];
      te[t * 2] = e0; te[t * 2 + 1] = e1;
      tw[t * 2] = p[e0] * inv; tw[t * 2 + 1] = p[e1] * inv;
    }
  }
}

// ---------------- sort: deterministic expert-bucket positions, single block, no atomics --
__global__ __launch_bounds__(1024) void sort_kernel(const int* __restrict__ te,
                                                    int* __restrict__ offs,
                                                    int* __restrict__ token_list,
                                                    int* __restrict__ tpos) {
  __shared__ int wsum[16][8];
  __shared__ int wbase[16][8];
  __shared__ int soffs[9];
  const int tid = threadIdx.x;
  const int wave = tid >> 6, lane = tid & 63;

  for (int j = tid; j < PMAX; j += 1024) token_list[j] = 0;

  const int t0 = tid * 4;
  int e_loc[8];
  int cnt[8];
#pragma unroll
  for (int e = 0; e < 8; e++) cnt[e] = 0;
#pragma unroll
  for (int k = 0; k < 8; k++) {
    int e = te[t0 * 2 + k];
    e_loc[k] = e;
    cnt[e]++;
  }
  int excl[8];
#pragma unroll
  for (int e = 0; e < 8; e++) {
    int v = cnt[e];
    int s = v;
#pragma unroll
    for (int d = 1; d < 64; d <<= 1) {
      int u = __shfl_up(s, d, 64);
      if (lane >= d) s += u;
    }
    excl[e] = s - v;
    if (lane == 63) wsum[wave][e] = s;
  }
  __syncthreads();
  if (tid < 8) {
    int e = tid;
    int a = 0;
    for (int w2 = 0; w2 < 16; w2++) { wbase[w2][e] = a; a += wsum[w2][e]; }
    wsum[0][e] = a;
  }
  __syncthreads();
  if (tid == 0) {
    int a = 0;
    for (int e = 0; e < 8; e++) {
      soffs[e] = a;
      a += (wsum[0][e] + 127) & ~127;
    }
    soffs[8] = a;
    for (int e = 0; e <= 8; e++) offs[e] = soffs[e];
  }
  __syncthreads();
  int base[8];
#pragma unroll
  for (int e = 0; e < 8; e++) base[e] = soffs[e] + wbase[wave][e] + excl[e];
#pragma unroll
  for (int k = 0; k < 8; k++) {
    int e = e_loc[k];
    int pos = base[e]++;
    int t = t0 + (k >> 1);
    token_list[pos] = t;
    tpos[t * 2 + (k & 1)] = pos;
  }
}

// ---------------- GEMM1: mid = silu(Xe @ Wg) * (Xe @ Wu) ----------------
// 128x128 tile, BK=64, xor-swizzled LDS, 32x32x16 MFMA, flattened 1D grid.
// launch_bounds(256,2): unified VGPR+AGPR ~232/wave -> 2 blocks/CU max (R6: (256,3) spills).
#define BK1 64

__global__ __launch_bounds__(256, 2) void gemm1_kernel(
    const u16* __restrict__ xb, const u16* __restrict__ wgt, const u16* __restrict__ wut,
    const int* __restrict__ token_list, const int* __restrict__ offs, u16* __restrict__ mid) {
  const int bid = blockIdx.x;
  const int my = bid >> 4, nx = bid & 15;
  const int grow0 = my * 128;  // global padded row of this tile
  if (grow0 >= offs[E_NUM]) return;
  int e = 0;
  while (offs[e + 1] <= grow0) e++;  // offs 128-aligned: tile never straddles experts
  const int n0 = nx * 128;

  __shared__ __align__(16) u16 As[128 * BK1];
  __shared__ __align__(16) u16 Bg[128 * BK1];
  __shared__ __align__(16) u16 Bu[128 * BK1];

  const int tid = threadIdx.x;
  const int wave = tid >> 6, lane = tid & 63;
  const int wm = (wave >> 1) * 64, wn = (wave & 1) * 64;
  const int l31 = lane & 31, kh = lane >> 5;

  f32x16 accg[2][2], accu[2][2];
#pragma unroll
  for (int i = 0; i < 2; i++)
#pragma unroll
    for (int j = 0; j < 2; j++) {
      accg[i][j] = (f32x16)(0.f);
      accu[i][j] = (f32x16)(0.f);
    }

  const u16* wgb = wgt + (size_t)e * I_DIM * H_DIM;
  const u16* wub = wut + (size_t)e * I_DIM * H_DIM;

  // staging: chunk c = tid + 256*i -> (row=c>>3, lds slot kcl=c&7); global chunk kg = kcl^(row&7)
  const u16* ga[4]; const u16* gg[4]; const u16* gu[4];
  u16 *la[4], *lg[4], *lu[4];
#pragma unroll
  for (int i = 0; i < 4; i++) {
    int c = tid + 256 * i;
    int row = c >> 3, kcl = c & 7;
    int kg = kcl ^ (row & 7);
    int tok = token_list[grow0 + row];  // padded rows -> token 0 (harmless)
    ga[i] = xb + (size_t)tok * H_DIM + kg * 8;
    gg[i] = wgb + (size_t)(n0 + row) * H_DIM + kg * 8;
    gu[i] = wub + (size_t)(n0 + row) * H_DIM + kg * 8;
    la[i] = &As[c * 8]; lg[i] = &Bg[c * 8]; lu[i] = &Bu[c * 8];
  }

  for (int kt = 0; kt < H_DIM / BK1; kt++) {
    const int k0 = kt * BK1;
#pragma unroll
    for (int i = 0; i < 4; i++) {
      async_ld16(ga[i] + k0, la[i]);
      async_ld16(gg[i] + k0, lg[i]);
      async_ld16(gu[i] + k0, lu[i]);
    }
    __syncthreads();
#pragma unroll
    for (int ks = 0; ks < 4; ks++) {  // K-steps of 16 within BK=64
      const int lc = ks * 2 + kh;     // this lane's logical 16B chunk
      short8 af[2], bgf[2], buf2[2];
#pragma unroll
      for (int mb = 0; mb < 2; mb++) {
        int row = wm + mb * 32 + l31;
        af[mb] = *(const short8*)(&As[row * BK1 + (lc ^ (row & 7)) * 8]);
      }
#pragma unroll
      for (int nb = 0; nb < 2; nb++) {
        int row = wn + nb * 32 + l31;
        int sl = (lc ^ (row & 7)) * 8;
        bgf[nb] = *(const short8*)(&Bg[row * BK1 + sl]);
        buf2[nb] = *(const short8*)(&Bu[row * BK1 + sl]);
      }
#pragma unroll
      for (int mb = 0; mb < 2; mb++)
#pragma unroll
        for (int nb = 0; nb < 2; nb++) {
          accg[mb][nb] = __builtin_amdgcn_mfma_f32_32x32x16_bf16(af[mb], bgf[nb], accg[mb][nb], 0, 0, 0);
          accu[mb][nb] = __builtin_amdgcn_mfma_f32_32x32x16_bf16(af[mb], buf2[nb], accu[mb][nb], 0, 0, 0);
        }
    }
    __syncthreads();
  }

  // C/D layout (m74/m101): col = lane&31, row = (reg&3) + 8*(reg>>2) + 4*(lane>>5)
#pragma unroll
  for (int mb = 0; mb < 2; mb++)
#pragma unroll
    for (int nb = 0; nb < 2; nb++) {
      u16* base = mid + (size_t)(grow0 + wm + mb * 32 + 4 * kh) * I_DIM + n0 + wn + nb * 32 + l31;
#pragma unroll
      for (int reg = 0; reg < 16; reg++) {
        int dr = (reg & 3) + 8 * (reg >> 2);
        float g = accg[mb][nb][reg];
        float u = accu[mb][nb][reg];
        float sv = g / (1.0f + __expf(-g)) * u;  // silu(g) * u
        base[(size_t)dr * I_DIM] = f2bf(sv);
      }
    }
}

// ---------------- GEMM2: eout = mid @ Wd^T  (dense bf16 store, no atomics) ----------------
__global__ __launch_bounds__(256, 2) void gemm2_kernel(
    const u16* __restrict__ mid, const u16* __restrict__ wdt,
    const int* __restrict__ offs, u16* __restrict__ eout) {
  const int bid = blockIdx.x;
  const int my = bid >> 3, nx = bid & 7;
  const int grow0 = my * 128;
  if (grow0 >= offs[E_NUM]) return;
  int e = 0;
  while (offs[e + 1] <= grow0) e++;
  const int n0 = nx * 128;

  __shared__ __align__(16) u16 As[128 * BK1];
  __shared__ __align__(16) u16 Bs[128 * BK1];

  const int tid = threadIdx.x;
  const int wave = tid >> 6, lane = tid & 63;
  const int wm = (wave >> 1) * 64, wn = (wave & 1) * 64;
  const int l31 = lane & 31, kh = lane >> 5;

  f32x16 acc[2][2];
#pragma unroll
  for (int i = 0; i < 2; i++)
#pragma unroll
    for (int j = 0; j < 2; j++) acc[i][j] = (f32x16)(0.f);

  const u16* wdb = wdt + (size_t)e * H_DIM * I_DIM;

  const u16* ga[4]; const u16* gb[4];
  u16 *la[4], *lb[4];
#pragma unroll
  for (int i = 0; i < 4; i++) {
    int c = tid + 256 * i;
    int row = c >> 3, kcl = c & 7;
    int kg = kcl ^ (row & 7);
    ga[i] = mid + (size_t)(grow0 + row) * I_DIM + kg * 8;
    gb[i] = wdb + (size_t)(n0 + row) * I_DIM + kg * 8;
    la[i] = &As[c * 8]; lb[i] = &Bs[c * 8];
  }

  for (int kt = 0; kt < I_DIM / BK1; kt++) {
    const int k0 = kt * BK1;
#pragma unroll
    for (int i = 0; i < 4; i++) {
      async_ld16(ga[i] + k0, la[i]);
      async_ld16(gb[i] + k0, lb[i]);
    }
    __syncthreads();
#pragma unroll
    for (int ks = 0; ks < 4; ks++) {
      const int lc = ks * 2 + kh;
      short8 af[2], bf[2];
#pragma unroll
      for (int mb = 0; mb < 2; mb++) {
        int row = wm + mb * 32 + l31;
        af[mb] = *(const short8*)(&As[row * BK1 + (lc ^ (row & 7)) * 8]);
      }
#pragma unroll
      for (int nb = 0; nb < 2; nb++) {
        int row = wn + nb * 32 + l31;
        bf[nb] = *(const short8*)(&Bs[row * BK1 + (lc ^ (row & 7)) * 8]);
      }
#pragma unroll
      for (int mb = 0; mb < 2; mb++)
#pragma unroll
        for (int nb = 0; nb < 2; nb++)
          acc[mb][nb] = __builtin_amdgcn_mfma_f32_32x32x16_bf16(af[mb], bf[nb], acc[mb][nb], 0, 0, 0);
    }
    __syncthreads();
  }

#pragma unroll
  for (int mb = 0; mb < 2; mb++)
#pragma unroll
    for (int nb = 0; nb < 2; nb++) {
      u16* base = eout + (size_t)(grow0 + wm + mb * 32 + 4 * kh) * H_DIM + n0 + wn + nb * 32 + l31;
#pragma unroll
      for (int reg = 0; reg < 16; reg++) {
        int dr = (reg & 3) + 8 * (reg >> 2);
        base[(size_t)dr * H_DIM] = f2bf(acc[mb][nb][reg]);
      }
    }
}

// ---------------- combine: out[t] = w0*eout[p0] + w1*eout[p1] ----------------
__global__ void combine_kernel(const u16* __restrict__ eout, const int* __restrict__ tpos,
                               const float* __restrict__ tw, float* __restrict__ out) {
  const int half = threadIdx.x >> 7;
  const int t = blockIdx.x * 2 + half;
  const int lt = threadIdx.x & 127;
  const int h0 = lt * 8;
  const int p0 = tpos[t * 2], p1 = tpos[t * 2 + 1];
  const float w0 = tw[t * 2], w1 = tw[t * 2 + 1];
  ushort4 a0 = *(const ushort4*)(eout + (size_t)p0 * H_DIM + h0);
  ushort4 a1 = *(const ushort4*)(eout + (size_t)p0 * H_DIM + h0 + 4);
  ushort4 b0 = *(const ushort4*)(eout + (size_t)p1 * H_DIM + h0);
  ushort4 b1 = *(const ushort4*)(eout + (size_t)p1 * H_DIM + h0 + 4);
  float4 o0, o1;
  o0.x = w0 * bf2f(a0.x) + w1 * bf2f(b0.x);
  o0.y = w0 * bf2f(a0.y) + w1 * bf2f(b0.y);
  o0.z = w0 * bf2f(a0.z) + w1 * bf2f(b0.z);
  o0.w = w0 * bf2f(a0.w) + w1 * bf2f(b0.w);
  o1.x = w0 * bf2f(a1.x) + w1 * bf2f(b1.x);
  o1.y = w0 * bf2f(a1.y) + w1 * bf2f(b1.y);
  o1.z = w0 * bf2f(a1.z) + w1 * bf2f(b1.z);
  o1.w = w0 * bf2f(a1.w) + w1 * bf2f(b1.w);
  float* orow = out + (size_t)t * H_DIM + h0;
  *(float4*)(orow) = o0;
  *(float4*)(orow + 4) = o1;
}

// ---------------- launch ----------------
extern "C" void kernel_launch(void* const* d_in, const int* in_sizes, int n_in,
                              void* d_out, int out_size, void* d_ws, size_t ws_size,
                              hipStream_t stream) {
  const float* x  = (const float*)d_in[0];   // [T, H]
  const float* gw = (const float*)d_in[1];   // [H, E]
  const float* Wg = (const float*)d_in[2];   // [E, H, I]
  const float* Wu = (const float*)d_in[3];   // [E, H, I]
  const float* Wd = (const float*)d_in[4];   // [E, I, H]
  float* out = (float*)d_out;                          // [T, H]
  float* out_logits = out + (size_t)T_TOK * H_DIM;     // [T, E]

  char* w = (char*)d_ws;
  size_t o = 0;
  auto take = [&](size_t bytes) { char* p = w + o; o += (bytes + 255) & ~(size_t)255; return p; };
  int*   offs        = (int*)take((E_NUM + 1) * 4);
  int*   te          = (int*)take((size_t)T_TOK * 2 * 4);
  float* tw          = (float*)take((size_t)T_TOK * 2 * 4);
  int*   token_list  = (int*)take((size_t)PMAX * 4);
  int*   tpos        = (int*)take((size_t)T_TOK * 2 * 4);
  u16*   xb          = (u16*)take((size_t)T_TOK * H_DIM * 2);
  u16*   wgt         = (u16*)take((size_t)E_NUM * H_DIM * I_DIM * 2);  // [E][I][H] bf16
  u16*   wut         = (u16*)take((size_t)E_NUM * H_DIM * I_DIM * 2);  // [E][I][H] bf16
  u16*   wdt         = (u16*)take((size_t)E_NUM * H_DIM * I_DIM * 2);  // [E][H][I] bf16
  u16*   mid         = (u16*)take((size_t)PMAX * I_DIM * 2);           // [PMAX][I] bf16
  // eout aliases wgt: gemm1 (last reader of wgt) completes before gemm2 writes eout
  u16*   eout        = wgt;                                            // [PMAX][H] bf16
  (void)in_sizes; (void)n_in; (void)out_size; (void)ws_size;

  front_kernel<<<WCONV_BLOCKS + ROUTER_BLOCKS, 256, 0, stream>>>(
      Wg, Wu, Wd, wgt, wut, wdt, x, xb, gw, out_logits, te, tw);
  sort_kernel<<<1, 1024, 0, stream>>>(te, offs, token_list, tpos);
  gemm1_kernel<<<(PMAX / 128) * (I_DIM / 128), 256, 0, stream>>>(xb, wgt, wut, token_list, offs, mid);
  gemm2_kernel<<<(PMAX / 128) * (H_DIM / 128), 256, 0, stream>>>(mid, wdt, offs, eout);
  combine_kernel<<<T_TOK / 2, 256, 0, stream>>>(eout, tpos, tw, out);
}